// Round 5
// baseline (78.615 us; speedup 1.0000x reference)
//
#include <hip/hip_runtime.h>
#include <hip/hip_bf16.h>

#define B_SZ 256
#define NCH 64
#define NPOS 121
#define NPATCH (B_SZ * NPOS)      // 30976
#define KTOT 192
#define RGB_W 264                 // 88*3 ints per image row
#define LDR 264                   // LDS image row stride (shorts), 528 B
#define LDB 200                   // LDS B row stride (shorts), 400 B (16B-aligned)
#define FST 68                    // feats-bits row stride (words)

typedef short bf16x8 __attribute__((ext_vector_type(8)));
typedef float f32x4 __attribute__((ext_vector_type(4)));

// round-to-nearest-even f32 -> bf16 (finite inputs)
static __device__ inline unsigned f2bf(float x) {
  union { float f; unsigned u; } a; a.f = x;
  return (a.u + 0x7FFFu + ((a.u >> 16) & 1u)) >> 16;
}
static __device__ inline unsigned pack2(float lo, float hi) {
  return f2bf(lo) | (f2bf(hi) << 16);
}

// LDS-only barrier: does NOT drain vmcnt, so global stores stay in flight.
// Fenced on both sides so the compiler can't move ds ops across it (rule #18).
static __device__ inline void light_barrier() {
  asm volatile("s_waitcnt lgkmcnt(0)" ::: "memory");
  __builtin_amdgcn_s_barrier();
  asm volatile("" ::: "memory");
}

// ---------------------------------------------------------------------------
// One block per batch, 512 threads (8 waves).
// conv (MFMA, no im2col) + bias + relu + full guidance, single launch.
// ---------------------------------------------------------------------------
__global__ __launch_bounds__(512) void fused(
    const int* __restrict__ rgb, const float* __restrict__ Wc,
    const float* __restrict__ bc, float* __restrict__ out,
    float* __restrict__ gout) {
  __shared__ __align__(16) unsigned short rgbL[88 * LDR];  // 46.5 KB (aliased later)
  __shared__ __align__(16) unsigned short BtL[NCH * LDB];  // 25.6 KB
  __shared__ unsigned sig[NPOS];
  __shared__ int counts[NPOS];
  __shared__ int redi[8];
  __shared__ float redf[8];
  unsigned* fbits = (unsigned*)rgbL;   // [NPOS][FST] words = 32.9 KB < 46.5 KB

  const int b = blockIdx.x, tid = threadIdx.x;
  const int lane = tid & 63, w = tid >> 6;   // 8 waves
  const int lr = lane & 15, lg = lane >> 4;

  // ---- bias early (no late vmem load behind the epilogue stores)
  float bias[4];
  #pragma unroll
  for (int ni = 0; ni < 4; ++ni) bias[ni] = bc[ni * 16 + lr];

  // ---- rgb deep loads FIRST (critical path): 5808 int4 = 11*512 + 176
  const int4* src4 = (const int4*)(rgb + (size_t)b * 88 * RGB_W);
  int4 r[11];
  #pragma unroll
  for (int it = 0; it < 11; ++it) r[it] = src4[tid + it * 512];
  int4 rt;
  const bool tail = (tid < 176);
  if (tail) rt = src4[5632 + tid];

  // ---- B: Wc[k][n] f32 -> BtL[n][k] bf16. Wave w owns k in [w*24, w*24+24).
  #pragma unroll
  for (int j = 0; j < 12; ++j) {
    const int k = w * 24 + 2 * j;
    *(unsigned*)&BtL[lane * LDB + k] =
        pack2(Wc[k * NCH + lane], Wc[(k + 1) * NCH + lane]);
  }

  // ---- convert + write image to LDS as bf16 [88][264]
  #pragma unroll
  for (int it = 0; it < 11; ++it) {
    const int i = tid + it * 512;
    const int e = i * 4, row = e / RGB_W, col = e - row * RGB_W;
    uint2 p;
    p.x = pack2((float)r[it].x * (1.f/255.f), (float)r[it].y * (1.f/255.f));
    p.y = pack2((float)r[it].z * (1.f/255.f), (float)r[it].w * (1.f/255.f));
    *(uint2*)&rgbL[row * LDR + col] = p;
  }
  if (tail) {
    const int i = 5632 + tid;
    const int e = i * 4, row = e / RGB_W, col = e - row * RGB_W;
    uint2 p;
    p.x = pack2((float)rt.x * (1.f/255.f), (float)rt.y * (1.f/255.f));
    p.y = pack2((float)rt.z * (1.f/255.f), (float)rt.w * (1.f/255.f));
    *(uint2*)&rgbL[row * LDR + col] = p;
  }
  __syncthreads();     // staging loads already consumed; full barrier is cheap here

  // ---- MFMA: wave w owns patch rows w*16..w*16+15, full N=64, K=192.
  // k0 = ks*32+lg*8 is a multiple of 8 -> never crosses a ky row (k%24 in
  // {0,8,16}) -> A-frag is a contiguous 16B slice of the staged image.
  const int p = w * 16 + lr;
  const int pe = p > 120 ? 120 : p;          // pad rows duplicate row 120
  const int oy = pe / 11, ox = pe - oy * 11;
  f32x4 acc[4] = {};
  #pragma unroll
  for (int ks = 0; ks < 6; ++ks) {
    const int k0 = ks * 32 + lg * 8;
    const int ky = k0 / 24, km = k0 - ky * 24;
    const bf16x8 a = *(const bf16x8*)&rgbL[(oy * 8 + ky) * LDR + ox * 24 + km];
    #pragma unroll
    for (int ni = 0; ni < 4; ++ni) {
      const bf16x8 bb = *(const bf16x8*)&BtL[(ni * 16 + lr) * LDB + k0];
      acc[ni] = __builtin_amdgcn_mfma_f32_16x16x32_bf16(a, bb, acc[ni], 0, 0, 0);
    }
  }
  __syncthreads();     // all rgbL reads done before aliasing; nothing in vmcnt

  // ---- epilogue: +bias, relu (+0 kills -0), store global + LDS bits,
  //      and compute per-row hash IN REGISTERS (xor-reduce across lr lanes)
  unsigned mult[4];
  #pragma unroll
  for (int ni = 0; ni < 4; ++ni)
    mult[ni] = (2u * (unsigned)(ni * 16 + lr) + 1u) * 0x9E3779B9u;
  float* outB = out + (size_t)b * NPOS * NCH;
  #pragma unroll
  for (int rr = 0; rr < 4; ++rr) {
    const int ps = w * 16 + lg * 4 + rr;     // uniform within each 16-lane group
    if (ps < NPOS) {
      unsigned ph = 0;
      #pragma unroll
      for (int ni = 0; ni < 4; ++ni) {
        const float v = fmaxf(acc[ni][rr] + bias[ni], 0.f) + 0.f;
        const unsigned bits = __float_as_uint(v);
        outB[ps * NCH + ni * 16 + lr] = v;       // fire-and-forget global store
        fbits[ps * FST + ni * 16 + lr] = bits;   // for collision verify only
        ph ^= (bits ^ (bits >> 15)) * mult[ni];
      }
      #pragma unroll
      for (int m = 1; m < 16; m <<= 1) ph ^= __shfl_xor(ph, m, 64);
      if (lr == 0) sig[ps] = ph;
    }
  }
  light_barrier();     // LDS visibility only; 31 MB of stores stays in flight

  // ---- counts via signature match (exact verify on collision, ~never taken)
  int cnt = 0x7fffffff;
  if (tid < NPOS) {
    const unsigned si = sig[tid];
    int m = 0;
    for (int j = 0; j < NPOS; ++j) m += (sig[j] == si) ? 1 : 0;
    cnt = 1;
    if (m > 1) {
      cnt = 0;
      for (int j = 0; j < NPOS; ++j) {
        if (sig[j] == si) {
          int eq = 1;
          for (int c = 0; c < NCH; ++c) eq &= (fbits[tid*FST + c] == fbits[j*FST + c]);
          cnt += eq;
        }
      }
    }
    counts[tid] = cnt;
  }
  // kmin wave reduce (all lanes execute shuffles)
  int km_ = cnt;
  #pragma unroll
  for (int m = 1; m < 64; m <<= 1) km_ = min(km_, __shfl_xor(km_, m, 64));
  if (lane == 0) redi[w] = km_;
  light_barrier();
  int kmin = redi[0];
  #pragma unroll
  for (int q = 1; q < 8; ++q) kmin = min(kmin, redi[q]);

  // ---- allow rule: cum[c_i] = #{j: counts[j] <= c_i}; parallel, no histogram
  float wv = 0.f;
  if (tid < NPOS) {
    int cum = 0;
    for (int j = 0; j < NPOS; ++j) cum += (counts[j] <= cnt) ? 1 : 0;
    if (cum <= 36 || cnt == kmin) wv = 1.f / (float)cnt;   // K = int(0.3*121)
  }
  float s = wv;
  #pragma unroll
  for (int m = 1; m < 64; m <<= 1) s += __shfl_xor(s, m, 64);
  if (lane == 0) redf[w] = s;
  light_barrier();
  float Z = redf[0];
  #pragma unroll
  for (int q = 1; q < 8; ++q) Z += redf[q];
  if (tid < NPOS) gout[(size_t)b * NPOS + tid] = wv / Z;
}

extern "C" void kernel_launch(void* const* d_in, const int* in_sizes, int n_in,
                              void* d_out, int out_size, void* d_ws, size_t ws_size,
                              hipStream_t stream) {
  const int*   rgb = (const int*)d_in[0];
  const float* Wc  = (const float*)d_in[1];
  const float* bc  = (const float*)d_in[2];
  float* out   = (float*)d_out;                        // vis_op: 30976 x 64
  float* guide = out + (size_t)NPATCH * NCH;           // guidance: 256 x 121

  fused<<<B_SZ, 512, 0, stream>>>(rgb, Wc, bc, out, guide);
}